// Round 5
// baseline (307.378 us; speedup 1.0000x reference)
//
#include <hip/hip_runtime.h>
#include <math.h>

// Problem constants
#define NB   4
#define SEQ  2048
#define NH   12
#define CIN  2304      // 3*768 floats per token
#define TM   64        // kv rows per chunk
#define NCH  (SEQ/TM)  // 32 chunks
#define TQ   128       // q rows per block (4 waves x 32 q)

typedef _Float16 half8 __attribute__((ext_vector_type(8)));
typedef _Float16 half4 __attribute__((ext_vector_type(4)));
typedef float    f32x4 __attribute__((ext_vector_type(4)));

// ZERO workspace: R3/R4 failures triangulate to d_ws overflow (R3: eager pass
// + replay fail = pristine-copy clobber; R4: eager fail = live-QKV clobber
// once attention started reading QKV directly). Everything lives in LDS now.
//
// LDS images (validated in R3 eager): 64x64 f16 tile = 64 rows x 128 B,
// 16B-group g of row r stored at g ^ (r&7)  -> all ds_read_b128 fragment
// octets and all staging writes are bank-conflict-free (<=2-way, free).
//
// One kernel, grid (16,12,4), block 256 = 4 waves; each block: 128 q rows.
// Per chunk: stage K (LN'd) + V (transposed) from registers prefetched the
// previous iteration; S^T = K x Q^T; shift-free softmax (|s|<=8 by LN bound);
// O^T = Vt x P with P round-tripped through wave-private swizzled LDS.
__global__ __launch_bounds__(256, 3)
void fused_ln_attn(const float* __restrict__ QKV,
                   const float* __restrict__ q_scale,
                   const float* __restrict__ q_bias,
                   const float* __restrict__ k_scale,
                   const float* __restrict__ k_bias,
                   float* __restrict__ out)
{
    // Ka: 8 KB | Vt: 8 KB | Qt/P: 16 KB  = 32 KB
    __shared__ __align__(16) unsigned char sm[32768];
    unsigned char* Ka = sm;
    unsigned char* Vt = sm + 8192;
    unsigned char* Qt = sm + 16384;

    const int tid  = threadIdx.x;
    const int L    = tid & 63;
    const int wv   = tid >> 6;
    const int n16  = L & 15;
    const int quad = L >> 4;
    const int sw   = n16 & 7;   // row-swizzle key for fragment reads
    const int r4   = L >> 2;    // staging: row within 16
    const int c4   = L & 3;     // staging: 16-float column group

    const int qt = blockIdx.x, h = blockIdx.y, b = blockIdx.z;
    const int q0 = qt * TQ;

    const float4* QKV4 = (const float4*)QKV;
    unsigned char* Pw = Qt + wv * 4096;   // wave-private P (2 strips x 2 KB)

    // K scale/bias for this lane's 16 d-columns (c4*16 .. +15)
    float4 ksr[4], kbr[4];
    #pragma unroll
    for (int i = 0; i < 4; ++i) {
        ksr[i] = ((const float4*)k_scale)[c4 * 4 + i];
        kbr[i] = ((const float4*)k_bias)[c4 * 4 + i];
    }

    // ---- prefetch chunk 0 K/V into registers ----
    // K: wave wv covers chunk rows wv*16+r4; lane loads 16 floats (4 x float4)
    // V: lane L = d; loads 16 kv rows (wv*16 .. +15), stride CIN
    float4 kx[4];
    float  vv[16];
    {
        const size_t kb4 = (size_t)(b*SEQ + 0*64 + wv*16 + r4) * 576 + 192 + h*16 + c4*4;
        #pragma unroll
        for (int i = 0; i < 4; ++i) kx[i] = QKV4[kb4 + i];
        const float* gv = QKV + (size_t)(b*SEQ + 0*64 + wv*16) * CIN + 1536 + h*64 + L;
        #pragma unroll
        for (int j = 0; j < 16; ++j) vv[j] = gv[(size_t)j * CIN];
    }

    // ---- Q prologue: LN 32 rows/wave (2 passes of 16), swizzled into Qt ----
    #pragma unroll
    for (int g = 0; g < 2; ++g) {
        const int row = wv*32 + g*16 + r4;     // 0..127
        const size_t base4 = (size_t)(b*SEQ + q0 + row) * 576 + h*16 + c4*4;
        float4 x[4];
        #pragma unroll
        for (int i = 0; i < 4; ++i) x[i] = QKV4[base4 + i];
        float s = 0.f, s2 = 0.f;
        #pragma unroll
        for (int i = 0; i < 4; ++i) {
            s  += x[i].x + x[i].y + x[i].z + x[i].w;
            s2 += x[i].x*x[i].x + x[i].y*x[i].y + x[i].z*x[i].z + x[i].w*x[i].w;
        }
        s  += __shfl_xor(s, 1);  s  += __shfl_xor(s, 2);
        s2 += __shfl_xor(s2, 1); s2 += __shfl_xor(s2, 2);
        float mu = s * 0.015625f;
        float rstd = rsqrtf(s2 * 0.015625f - mu*mu + 1e-6f);
        float nb0 = -mu * rstd;
        half8 h0, h1;
        #pragma unroll
        for (int i = 0; i < 4; ++i) {
            float4 sc = ((const float4*)q_scale)[c4*4 + i];
            float4 bi = ((const float4*)q_bias)[c4*4 + i];
            float e0 = (fmaf(x[i].x, rstd, nb0) * sc.x + bi.x) * 0.125f;
            float e1 = (fmaf(x[i].y, rstd, nb0) * sc.y + bi.y) * 0.125f;
            float e2 = (fmaf(x[i].z, rstd, nb0) * sc.z + bi.z) * 0.125f;
            float e3 = (fmaf(x[i].w, rstd, nb0) * sc.w + bi.w) * 0.125f;
            if (i < 2) { h0[i*4+0]=(_Float16)e0; h0[i*4+1]=(_Float16)e1; h0[i*4+2]=(_Float16)e2; h0[i*4+3]=(_Float16)e3; }
            else { int j=(i-2)*4; h1[j+0]=(_Float16)e0; h1[j+1]=(_Float16)e1; h1[j+2]=(_Float16)e2; h1[j+3]=(_Float16)e3; }
        }
        *(half8*)(Qt + row*128 + (((2*c4+0) ^ (r4 & 7)) * 16)) = h0;
        *(half8*)(Qt + row*128 + (((2*c4+1) ^ (r4 & 7)) * 16)) = h1;
    }

    // Q fragments to registers (wave-private rows; same-wave DS is ordered)
    half8 qf[2][2];
    #pragma unroll
    for (int s = 0; s < 2; ++s) {
        const unsigned char* qrow = Qt + (wv*32 + s*16 + n16)*128;
        #pragma unroll
        for (int ks = 0; ks < 2; ++ks)
            qf[s][ks] = *(const half8*)(qrow + (((quad + 4*ks) ^ sw) * 16));
    }

    f32x4 oacc[2][4] = {};
    float lsum[2] = {0.f, 0.f};

    for (int mc = 0; mc < NCH; ++mc) {
        __syncthreads();   // prev chunk's fragment reads done; Qt reads done (mc=0)

        // ---- stage K: LN on prefetched kx -> swizzled Ka ----
        {
            const int row = wv*16 + r4;        // tile row 0..63
            float s = 0.f, s2 = 0.f;
            #pragma unroll
            for (int i = 0; i < 4; ++i) {
                s  += kx[i].x + kx[i].y + kx[i].z + kx[i].w;
                s2 += kx[i].x*kx[i].x + kx[i].y*kx[i].y + kx[i].z*kx[i].z + kx[i].w*kx[i].w;
            }
            s  += __shfl_xor(s, 1);  s  += __shfl_xor(s, 2);
            s2 += __shfl_xor(s2, 1); s2 += __shfl_xor(s2, 2);
            float mu = s * 0.015625f;
            float rstd = rsqrtf(s2 * 0.015625f - mu*mu + 1e-6f);
            float nb0 = -mu * rstd;
            half8 h0, h1;
            #pragma unroll
            for (int i = 0; i < 4; ++i) {
                float e0 = fmaf(kx[i].x, rstd, nb0) * ksr[i].x + kbr[i].x;
                float e1 = fmaf(kx[i].y, rstd, nb0) * ksr[i].y + kbr[i].y;
                float e2 = fmaf(kx[i].z, rstd, nb0) * ksr[i].z + kbr[i].z;
                float e3 = fmaf(kx[i].w, rstd, nb0) * ksr[i].w + kbr[i].w;
                if (i < 2) { h0[i*4+0]=(_Float16)e0; h0[i*4+1]=(_Float16)e1; h0[i*4+2]=(_Float16)e2; h0[i*4+3]=(_Float16)e3; }
                else { int j=(i-2)*4; h1[j+0]=(_Float16)e0; h1[j+1]=(_Float16)e1; h1[j+2]=(_Float16)e2; h1[j+3]=(_Float16)e3; }
            }
            *(half8*)(Ka + row*128 + (((2*c4+0) ^ (row & 7)) * 16)) = h0;
            *(half8*)(Ka + row*128 + (((2*c4+1) ^ (row & 7)) * 16)) = h1;
        }
        // ---- stage V: pack prefetched vv -> swizzled Vt (lane = d) ----
        {
            half8 a0, a1;
            #pragma unroll
            for (int j = 0; j < 8; ++j) { a0[j] = (_Float16)vv[j]; a1[j] = (_Float16)vv[j+8]; }
            *(half8*)(Vt + L*128 + (((2*wv+0) ^ (L & 7)) * 16)) = a0;
            *(half8*)(Vt + L*128 + (((2*wv+1) ^ (L & 7)) * 16)) = a1;
        }
        __syncthreads();   // staging visible

        // ---- prefetch chunk mc+1 (latency hidden by compute below) ----
        if (mc + 1 < NCH) {
            const size_t kb4 = (size_t)(b*SEQ + (mc+1)*64 + wv*16 + r4) * 576 + 192 + h*16 + c4*4;
            #pragma unroll
            for (int i = 0; i < 4; ++i) kx[i] = QKV4[kb4 + i];
            const float* gv = QKV + (size_t)(b*SEQ + (mc+1)*64 + wv*16) * CIN + 1536 + h*64 + L;
            #pragma unroll
            for (int j = 0; j < 16; ++j) vv[j] = gv[(size_t)j * CIN];
        }

        // ---- S^T = K x Q^T : 16 MFMAs, K A-frags shared across strips ----
        f32x4 sacc[2][4] = {};
        #pragma unroll
        for (int ks = 0; ks < 2; ++ks) {
            half8 ak[4];
            #pragma unroll
            for (int mt = 0; mt < 4; ++mt)
                ak[mt] = *(const half8*)(Ka + (16*mt + n16)*128 + (((quad + 4*ks) ^ sw) * 16));
            #pragma unroll
            for (int s = 0; s < 2; ++s)
                #pragma unroll
                for (int mt = 0; mt < 4; ++mt)
                    sacc[s][mt] = __builtin_amdgcn_mfma_f32_16x16x32_f16(ak[mt], qf[s][ks], sacc[s][mt], 0, 0, 0);
        }

        // ---- softmax, no max shift (|s| <= 8 by LN norm bound) ----
        #pragma unroll
        for (int s = 0; s < 2; ++s) {
            float ls = 0.f;
            #pragma unroll
            for (int mt = 0; mt < 4; ++mt) {
                float p0 = __expf(sacc[s][mt][0]);
                float p1 = __expf(sacc[s][mt][1]);
                float p2 = __expf(sacc[s][mt][2]);
                float p3 = __expf(sacc[s][mt][3]);
                ls += (p0 + p1) + (p2 + p3);
                half4 hp; hp[0]=(_Float16)p0; hp[1]=(_Float16)p1; hp[2]=(_Float16)p2; hp[3]=(_Float16)p3;
                *(half4*)(Pw + s*2048 + n16*128 + (((4*mt + quad) ^ n16) * 8)) = hp;
            }
            ls += __shfl_xor(ls, 16);
            ls += __shfl_xor(ls, 32);
            lsum[s] += ls;
        }

        // ---- O^T += Vt x P : 16 MFMAs (P wave-private: no barrier) ----
        #pragma unroll
        for (int ks = 0; ks < 2; ++ks) {
            half8 av[4];
            #pragma unroll
            for (int mt = 0; mt < 4; ++mt)
                av[mt] = *(const half8*)(Vt + (16*mt + n16)*128 + (((quad + 4*ks) ^ sw) * 16));
            #pragma unroll
            for (int s = 0; s < 2; ++s) {
                half4 b0 = *(const half4*)(Pw + s*2048 + n16*128 + (((8*ks + 2*quad + 0) ^ n16) * 8));
                half4 b1 = *(const half4*)(Pw + s*2048 + n16*128 + (((8*ks + 2*quad + 1) ^ n16) * 8));
                half8 bp;
                #pragma unroll
                for (int j = 0; j < 4; ++j) { bp[j] = b0[j]; bp[4+j] = b1[j]; }
                #pragma unroll
                for (int mt = 0; mt < 4; ++mt)
                    oacc[s][mt] = __builtin_amdgcn_mfma_f32_16x16x32_f16(av[mt], bp, oacc[s][mt], 0, 0, 0);
            }
        }
    }

    // ---- epilogue: lane owns q (per strip), d = 16mt + 4quad + r ----
    float4* out4 = (float4*)out;
    #pragma unroll
    for (int s = 0; s < 2; ++s) {
        float inv = 1.0f / lsum[s];
        size_t rowb = ((size_t)(b*NH + h)*SEQ + q0 + wv*32 + s*16 + n16) * 16;
        #pragma unroll
        for (int mt = 0; mt < 4; ++mt)
            out4[rowb + mt*4 + quad] = make_float4(oacc[s][mt][0]*inv, oacc[s][mt][1]*inv,
                                                   oacc[s][mt][2]*inv, oacc[s][mt][3]*inv);
    }
}

extern "C" void kernel_launch(void* const* d_in, const int* in_sizes, int n_in,
                              void* d_out, int out_size, void* d_ws, size_t ws_size,
                              hipStream_t stream) {
    const float* QKV     = (const float*)d_in[0];
    const float* q_scale = (const float*)d_in[1];
    const float* q_bias  = (const float*)d_in[2];
    const float* k_scale = (const float*)d_in[3];
    const float* k_bias  = (const float*)d_in[4];
    float* out = (float*)d_out;

    dim3 grid(SEQ / TQ, NH, NB);  // 16 x 12 x 4 = 768 blocks = 3/CU
    fused_ln_attn<<<grid, 256, 0, stream>>>(
        QKV, q_scale, q_bias, k_scale, k_bias, out);
}

// Round 6
// 259.504 us; speedup vs baseline: 1.1845x; 1.1845x over previous
//
#include <hip/hip_runtime.h>
#include <math.h>

// Problem constants
#define NB   4
#define SEQ  2048
#define NH   12
#define CIN  2304      // 3*768 floats per token
#define TM   64        // kv rows per chunk
#define NCH  (SEQ/TM)  // 32 chunks
#define TQ   128       // q rows per block (4 waves x 32 q)

typedef _Float16 half8 __attribute__((ext_vector_type(8)));
typedef _Float16 half4 __attribute__((ext_vector_type(4)));
typedef float    f32x4 __attribute__((ext_vector_type(4)));

// R5 kernel + XCD-aware block swizzle.
// R5 counters: VALUBusy 24%, MfmaUtil 9.5%, HBM 25%, 0 conflicts -> latency
// bound on K/V re-reads missing per-XCD L2 (16 blocks sharing a (b,h) were
// spread across all 8 XCDs). Flat grid 768, decoded so all 16 q-tiles of one
// (b,h) share id%8 -> same XCD (round-robin dispatch) -> K/V chunk reads
// become XCD-local L2 hits, hidden by the 1-chunk register prefetch.
__global__ __launch_bounds__(256, 3)
void fused_ln_attn(const float* __restrict__ QKV,
                   const float* __restrict__ q_scale,
                   const float* __restrict__ q_bias,
                   const float* __restrict__ k_scale,
                   const float* __restrict__ k_bias,
                   float* __restrict__ out)
{
    // Ka: 8 KB | Vt: 8 KB | Qt/P: 16 KB  = 32 KB
    __shared__ __align__(16) unsigned char sm[32768];
    unsigned char* Ka = sm;
    unsigned char* Vt = sm + 8192;
    unsigned char* Qt = sm + 16384;

    const int tid  = threadIdx.x;
    const int L    = tid & 63;
    const int wv   = tid >> 6;
    const int n16  = L & 15;
    const int quad = L >> 4;
    const int sw   = n16 & 7;   // row-swizzle key for fragment reads
    const int r4   = L >> 2;    // staging: row within 16
    const int c4   = L & 3;     // staging: 16-float column group

    // XCD swizzle: id = (grp*16 + qt)*8 + xcd ; bh = grp*8 + xcd (0..47)
    const int id  = blockIdx.x;
    const int xcd = id & 7;
    const int qt  = (id >> 3) & 15;
    const int grp = id >> 7;          // 0..5
    const int bh  = grp * 8 + xcd;    // 0..47
    const int b   = bh / NH;
    const int h   = bh - b * NH;
    const int q0  = qt * TQ;

    const float4* QKV4 = (const float4*)QKV;
    unsigned char* Pw = Qt + wv * 4096;   // wave-private P (2 strips x 2 KB)

    // K scale/bias for this lane's 16 d-columns (c4*16 .. +15)
    float4 ksr[4], kbr[4];
    #pragma unroll
    for (int i = 0; i < 4; ++i) {
        ksr[i] = ((const float4*)k_scale)[c4 * 4 + i];
        kbr[i] = ((const float4*)k_bias)[c4 * 4 + i];
    }

    // ---- prefetch chunk 0 K/V into registers ----
    float4 kx[4];
    float  vv[16];
    {
        const size_t kb4 = (size_t)(b*SEQ + wv*16 + r4) * 576 + 192 + h*16 + c4*4;
        #pragma unroll
        for (int i = 0; i < 4; ++i) kx[i] = QKV4[kb4 + i];
        const float* gv = QKV + (size_t)(b*SEQ + wv*16) * CIN + 1536 + h*64 + L;
        #pragma unroll
        for (int j = 0; j < 16; ++j) vv[j] = gv[(size_t)j * CIN];
    }

    // ---- Q prologue: LN 32 rows/wave (2 passes of 16), swizzled into Qt ----
    #pragma unroll
    for (int g = 0; g < 2; ++g) {
        const int row = wv*32 + g*16 + r4;     // 0..127
        const size_t base4 = (size_t)(b*SEQ + q0 + row) * 576 + h*16 + c4*4;
        float4 x[4];
        #pragma unroll
        for (int i = 0; i < 4; ++i) x[i] = QKV4[base4 + i];
        float s = 0.f, s2 = 0.f;
        #pragma unroll
        for (int i = 0; i < 4; ++i) {
            s  += x[i].x + x[i].y + x[i].z + x[i].w;
            s2 += x[i].x*x[i].x + x[i].y*x[i].y + x[i].z*x[i].z + x[i].w*x[i].w;
        }
        s  += __shfl_xor(s, 1);  s  += __shfl_xor(s, 2);
        s2 += __shfl_xor(s2, 1); s2 += __shfl_xor(s2, 2);
        float mu = s * 0.015625f;
        float rstd = rsqrtf(s2 * 0.015625f - mu*mu + 1e-6f);
        float nb0 = -mu * rstd;
        half8 h0, h1;
        #pragma unroll
        for (int i = 0; i < 4; ++i) {
            float4 sc = ((const float4*)q_scale)[c4*4 + i];
            float4 bi = ((const float4*)q_bias)[c4*4 + i];
            float e0 = (fmaf(x[i].x, rstd, nb0) * sc.x + bi.x) * 0.125f;
            float e1 = (fmaf(x[i].y, rstd, nb0) * sc.y + bi.y) * 0.125f;
            float e2 = (fmaf(x[i].z, rstd, nb0) * sc.z + bi.z) * 0.125f;
            float e3 = (fmaf(x[i].w, rstd, nb0) * sc.w + bi.w) * 0.125f;
            if (i < 2) { h0[i*4+0]=(_Float16)e0; h0[i*4+1]=(_Float16)e1; h0[i*4+2]=(_Float16)e2; h0[i*4+3]=(_Float16)e3; }
            else { int j=(i-2)*4; h1[j+0]=(_Float16)e0; h1[j+1]=(_Float16)e1; h1[j+2]=(_Float16)e2; h1[j+3]=(_Float16)e3; }
        }
        *(half8*)(Qt + row*128 + (((2*c4+0) ^ (r4 & 7)) * 16)) = h0;
        *(half8*)(Qt + row*128 + (((2*c4+1) ^ (r4 & 7)) * 16)) = h1;
    }

    // Q fragments to registers (wave-private rows; same-wave DS is ordered)
    half8 qf[2][2];
    #pragma unroll
    for (int s = 0; s < 2; ++s) {
        const unsigned char* qrow = Qt + (wv*32 + s*16 + n16)*128;
        #pragma unroll
        for (int ks = 0; ks < 2; ++ks)
            qf[s][ks] = *(const half8*)(qrow + (((quad + 4*ks) ^ sw) * 16));
    }

    f32x4 oacc[2][4] = {};
    float lsum[2] = {0.f, 0.f};

    for (int mc = 0; mc < NCH; ++mc) {
        __syncthreads();   // prev chunk's fragment reads done; Qt reads done (mc=0)

        // ---- stage K: LN on prefetched kx -> swizzled Ka ----
        {
            const int row = wv*16 + r4;        // tile row 0..63
            float s = 0.f, s2 = 0.f;
            #pragma unroll
            for (int i = 0; i < 4; ++i) {
                s  += kx[i].x + kx[i].y + kx[i].z + kx[i].w;
                s2 += kx[i].x*kx[i].x + kx[i].y*kx[i].y + kx[i].z*kx[i].z + kx[i].w*kx[i].w;
            }
            s  += __shfl_xor(s, 1);  s  += __shfl_xor(s, 2);
            s2 += __shfl_xor(s2, 1); s2 += __shfl_xor(s2, 2);
            float mu = s * 0.015625f;
            float rstd = rsqrtf(s2 * 0.015625f - mu*mu + 1e-6f);
            float nb0 = -mu * rstd;
            half8 h0, h1;
            #pragma unroll
            for (int i = 0; i < 4; ++i) {
                float e0 = fmaf(kx[i].x, rstd, nb0) * ksr[i].x + kbr[i].x;
                float e1 = fmaf(kx[i].y, rstd, nb0) * ksr[i].y + kbr[i].y;
                float e2 = fmaf(kx[i].z, rstd, nb0) * ksr[i].z + kbr[i].z;
                float e3 = fmaf(kx[i].w, rstd, nb0) * ksr[i].w + kbr[i].w;
                if (i < 2) { h0[i*4+0]=(_Float16)e0; h0[i*4+1]=(_Float16)e1; h0[i*4+2]=(_Float16)e2; h0[i*4+3]=(_Float16)e3; }
                else { int j=(i-2)*4; h1[j+0]=(_Float16)e0; h1[j+1]=(_Float16)e1; h1[j+2]=(_Float16)e2; h1[j+3]=(_Float16)e3; }
            }
            *(half8*)(Ka + row*128 + (((2*c4+0) ^ (row & 7)) * 16)) = h0;
            *(half8*)(Ka + row*128 + (((2*c4+1) ^ (row & 7)) * 16)) = h1;
        }
        // ---- stage V: pack prefetched vv -> swizzled Vt (lane = d) ----
        {
            half8 a0, a1;
            #pragma unroll
            for (int j = 0; j < 8; ++j) { a0[j] = (_Float16)vv[j]; a1[j] = (_Float16)vv[j+8]; }
            *(half8*)(Vt + L*128 + (((2*wv+0) ^ (L & 7)) * 16)) = a0;
            *(half8*)(Vt + L*128 + (((2*wv+1) ^ (L & 7)) * 16)) = a1;
        }
        __syncthreads();   // staging visible

        // ---- prefetch chunk mc+1 (latency hidden by compute below) ----
        if (mc + 1 < NCH) {
            const size_t kb4 = (size_t)(b*SEQ + (mc+1)*64 + wv*16 + r4) * 576 + 192 + h*16 + c4*4;
            #pragma unroll
            for (int i = 0; i < 4; ++i) kx[i] = QKV4[kb4 + i];
            const float* gv = QKV + (size_t)(b*SEQ + (mc+1)*64 + wv*16) * CIN + 1536 + h*64 + L;
            #pragma unroll
            for (int j = 0; j < 16; ++j) vv[j] = gv[(size_t)j * CIN];
        }

        // ---- S^T = K x Q^T : 16 MFMAs, K A-frags shared across strips ----
        f32x4 sacc[2][4] = {};
        #pragma unroll
        for (int ks = 0; ks < 2; ++ks) {
            half8 ak[4];
            #pragma unroll
            for (int mt = 0; mt < 4; ++mt)
                ak[mt] = *(const half8*)(Ka + (16*mt + n16)*128 + (((quad + 4*ks) ^ sw) * 16));
            #pragma unroll
            for (int s = 0; s < 2; ++s)
                #pragma unroll
                for (int mt = 0; mt < 4; ++mt)
                    sacc[s][mt] = __builtin_amdgcn_mfma_f32_16x16x32_f16(ak[mt], qf[s][ks], sacc[s][mt], 0, 0, 0);
        }

        // ---- softmax, no max shift (|s| <= 8 by LN norm bound) ----
        #pragma unroll
        for (int s = 0; s < 2; ++s) {
            float ls = 0.f;
            #pragma unroll
            for (int mt = 0; mt < 4; ++mt) {
                float p0 = __expf(sacc[s][mt][0]);
                float p1 = __expf(sacc[s][mt][1]);
                float p2 = __expf(sacc[s][mt][2]);
                float p3 = __expf(sacc[s][mt][3]);
                ls += (p0 + p1) + (p2 + p3);
                half4 hp; hp[0]=(_Float16)p0; hp[1]=(_Float16)p1; hp[2]=(_Float16)p2; hp[3]=(_Float16)p3;
                *(half4*)(Pw + s*2048 + n16*128 + (((4*mt + quad) ^ n16) * 8)) = hp;
            }
            ls += __shfl_xor(ls, 16);
            ls += __shfl_xor(ls, 32);
            lsum[s] += ls;
        }

        // ---- O^T += Vt x P : 16 MFMAs (P wave-private: no barrier) ----
        #pragma unroll
        for (int ks = 0; ks < 2; ++ks) {
            half8 av[4];
            #pragma unroll
            for (int mt = 0; mt < 4; ++mt)
                av[mt] = *(const half8*)(Vt + (16*mt + n16)*128 + (((quad + 4*ks) ^ sw) * 16));
            #pragma unroll
            for (int s = 0; s < 2; ++s) {
                half4 b0 = *(const half4*)(Pw + s*2048 + n16*128 + (((8*ks + 2*quad + 0) ^ n16) * 8));
                half4 b1 = *(const half4*)(Pw + s*2048 + n16*128 + (((8*ks + 2*quad + 1) ^ n16) * 8));
                half8 bp;
                #pragma unroll
                for (int j = 0; j < 4; ++j) { bp[j] = b0[j]; bp[4+j] = b1[j]; }
                #pragma unroll
                for (int mt = 0; mt < 4; ++mt)
                    oacc[s][mt] = __builtin_amdgcn_mfma_f32_16x16x32_f16(av[mt], bp, oacc[s][mt], 0, 0, 0);
            }
        }
    }

    // ---- epilogue: lane owns q (per strip), d = 16mt + 4quad + r ----
    float4* out4 = (float4*)out;
    #pragma unroll
    for (int s = 0; s < 2; ++s) {
        float inv = 1.0f / lsum[s];
        size_t rowb = ((size_t)(b*NH + h)*SEQ + q0 + wv*32 + s*16 + n16) * 16;
        #pragma unroll
        for (int mt = 0; mt < 4; ++mt)
            out4[rowb + mt*4 + quad] = make_float4(oacc[s][mt][0]*inv, oacc[s][mt][1]*inv,
                                                   oacc[s][mt][2]*inv, oacc[s][mt][3]*inv);
    }
}

extern "C" void kernel_launch(void* const* d_in, const int* in_sizes, int n_in,
                              void* d_out, int out_size, void* d_ws, size_t ws_size,
                              hipStream_t stream) {
    const float* QKV     = (const float*)d_in[0];
    const float* q_scale = (const float*)d_in[1];
    const float* q_bias  = (const float*)d_in[2];
    const float* k_scale = (const float*)d_in[3];
    const float* k_bias  = (const float*)d_in[4];
    float* out = (float*)d_out;

    // flat 768-block grid, decoded inside for XCD-locality of K/V sharers
    fused_ln_attn<<<dim3(NB * NH * (SEQ / TQ)), 256, 0, stream>>>(
        QKV, q_scale, q_bias, k_scale, k_bias, out);
}